// Round 5
// baseline (161.015 us; speedup 1.0000x reference)
//
#include <hip/hip_runtime.h>
#include <math.h>

#define FIN   64
#define NK    512
#define FOUT  256
#define BB    8             // batch rows per block
#define NTHR  512           // 8 waves
#define RSTR  (NK + 4)      // padded R stride (floats)

__device__ __forceinline__ float dot4(float4 a, float4 b, float s) {
    s = fmaf(a.x, b.x, s);
    s = fmaf(a.y, b.y, s);
    s = fmaf(a.z, b.z, s);
    s = fmaf(a.w, b.w, s);
    return s;
}

__global__ __launch_bounds__(NTHR, 4) void rbf_fused_kernel(
    const float* __restrict__ x,     // [B][FIN]
    const float* __restrict__ w,     // [FOUT][NK]
    const float* __restrict__ cent,  // [NK][FIN]
    const float* __restrict__ ls,    // [NK]
    float* __restrict__ out)         // [B][FOUT]
{
    __shared__ float xs[BB * FIN];   // 2 KB
    __shared__ float Rs[BB * RSTR];  // 16.5 KB unnormalized rbf
    __shared__ float xsq[BB];
    __shared__ float invs[BB];

    const int tid = threadIdx.x;
    const int b0  = blockIdx.x * BB;

    // ---- stage x tile: 128 float4, coalesced ----
    if (tid < 128) {
        const float4* xg = (const float4*)(x + (size_t)b0 * FIN);
        ((float4*)xs)[tid] = xg[tid];
    }
    __syncthreads();

    // ---- xsq[r]: wave r reduces row r (8 waves <-> 8 rows) ----
    {
        const int wv = tid >> 6, ln = tid & 63;
        const float v = xs[wv * FIN + ln];
        float s = v * v;
        #pragma unroll
        for (int m = 32; m >= 1; m >>= 1) s += __shfl_xor(s, m);
        if (ln == 0) xsq[wv] = s;
    }
    __syncthreads();

    // ---- phase 1: rbf via ||x||^2 - 2 x.c + ||c||^2 ----
    // thread = (kk, jc): jc covers dims [16jc,16jc+16); 4 consecutive lanes
    // form one contiguous 256B cent row read. NO runtime-indexed register
    // arrays anywhere (spill trap).
    {
        const int kk = tid >> 2;   // 0..127
        const int jc = tid & 3;
        #pragma unroll 1
        for (int p = 0; p < 4; ++p) {
            const int k = kk + 128 * p;
            const float4* cg = (const float4*)(cent + (size_t)k * FIN + 16 * jc);
            const float4 c0 = cg[0], c1 = cg[1], c2 = cg[2], c3 = cg[3];
            float csq = dot4(c3, c3, dot4(c2, c2, dot4(c1, c1, dot4(c0, c0, 0.f))));
            csq += __shfl_xor(csq, 1);
            csq += __shfl_xor(csq, 2);
            const float e2 = __expf(2.f * ls[k]);
            #pragma unroll
            for (int g = 0; g < 2; ++g) {
                const float* xb = xs + (4 * g) * FIN + 16 * jc;
                float cr0, cr1, cr2, cr3;
                {
                    const float4* xp = (const float4*)(xb + 0 * FIN);
                    cr0 = dot4(xp[3], c3, dot4(xp[2], c2, dot4(xp[1], c1, dot4(xp[0], c0, 0.f))));
                }
                {
                    const float4* xp = (const float4*)(xb + 1 * FIN);
                    cr1 = dot4(xp[3], c3, dot4(xp[2], c2, dot4(xp[1], c1, dot4(xp[0], c0, 0.f))));
                }
                {
                    const float4* xp = (const float4*)(xb + 2 * FIN);
                    cr2 = dot4(xp[3], c3, dot4(xp[2], c2, dot4(xp[1], c1, dot4(xp[0], c0, 0.f))));
                }
                {
                    const float4* xp = (const float4*)(xb + 3 * FIN);
                    cr3 = dot4(xp[3], c3, dot4(xp[2], c2, dot4(xp[1], c1, dot4(xp[0], c0, 0.f))));
                }
                // fold dim-chunks across the 4 jc lanes
                cr0 += __shfl_xor(cr0, 1); cr0 += __shfl_xor(cr0, 2);
                cr1 += __shfl_xor(cr1, 1); cr1 += __shfl_xor(cr1, 2);
                cr2 += __shfl_xor(cr2, 1); cr2 += __shfl_xor(cr2, 2);
                cr3 += __shfl_xor(cr3, 1); cr3 += __shfl_xor(cr3, 2);
                // lane jc owns row 4g+jc — static select, NOT cr[jc]
                const float cr = (jc == 0) ? cr0 : (jc == 1) ? cr1 : (jc == 2) ? cr2 : cr3;
                const int row = 4 * g + jc;
                const float ssq = fmaf(-2.f, cr, xsq[row] + csq);
                Rs[row * RSTR + k] = __expf(-(e2 * ssq));
            }
        }
    }
    __syncthreads();

    // ---- row sums: wave r reduces Rs[r][:] ----
    {
        const int wv = tid >> 6, ln = tid & 63;
        const float4* rp = (const float4*)(Rs + wv * RSTR + 8 * ln);
        const float4 a = rp[0], b = rp[1];
        float s = ((a.x + a.y) + (a.z + a.w)) + ((b.x + b.y) + (b.z + b.w));
        #pragma unroll
        for (int m = 32; m >= 1; m >>= 1) s += __shfl_xor(s, m);
        if (ln == 0) invs[wv] = 1.f / (1e-9f + s);
    }
    __syncthreads();

    // ---- phase 2: out[8][256] = Rs * W^T, W streamed from L2 ----
    // thread: 1 row x 4 cols; wave = 8 rows x 32 cols, disjoint W per wave.
    {
        const int row  = tid & 7;
        const int col0 = 4 * (tid >> 3);
        const float* wp0 = w + (size_t)(col0 + 0) * NK;
        const float* wp1 = w + (size_t)(col0 + 1) * NK;
        const float* wp2 = w + (size_t)(col0 + 2) * NK;
        const float* wp3 = w + (size_t)(col0 + 3) * NK;
        const float* rp  = Rs + row * RSTR;

        float a0 = 0.f, a1 = 0.f, a2 = 0.f, a3 = 0.f;
        float4 rf = *(const float4*)rp;
        float4 w0 = *(const float4*)wp0;
        float4 w1 = *(const float4*)wp1;
        float4 w2 = *(const float4*)wp2;
        float4 w3 = *(const float4*)wp3;

        #pragma unroll 4
        for (int s = 0; s < NK / 4 - 1; ++s) {
            const int kn = 4 * (s + 1);
            const float4 rfn = *(const float4*)(rp + kn);
            const float4 w0n = *(const float4*)(wp0 + kn);
            const float4 w1n = *(const float4*)(wp1 + kn);
            const float4 w2n = *(const float4*)(wp2 + kn);
            const float4 w3n = *(const float4*)(wp3 + kn);
            a0 = dot4(rf, w0, a0);
            a1 = dot4(rf, w1, a1);
            a2 = dot4(rf, w2, a2);
            a3 = dot4(rf, w3, a3);
            rf = rfn; w0 = w0n; w1 = w1n; w2 = w2n; w3 = w3n;
        }
        a0 = dot4(rf, w0, a0);
        a1 = dot4(rf, w1, a1);
        a2 = dot4(rf, w2, a2);
        a3 = dot4(rf, w3, a3);

        const float iv = invs[row];
        float4 o;
        o.x = a0 * iv;
        o.y = a1 * iv;
        o.z = a2 * iv;
        o.w = a3 * iv;
        *(float4*)(out + (size_t)(b0 + row) * FOUT + col0) = o;
    }
}

extern "C" void kernel_launch(void* const* d_in, const int* in_sizes, int n_in,
                              void* d_out, int out_size, void* d_ws, size_t ws_size,
                              hipStream_t stream) {
    const float* x    = (const float*)d_in[0];   // [4096][64]
    const float* w    = (const float*)d_in[1];   // [256][512]
    const float* cent = (const float*)d_in[2];   // [512][64]
    const float* ls   = (const float*)d_in[3];   // [512]
    float* out        = (float*)d_out;           // [4096][256]

    rbf_fused_kernel<<<dim3(4096 / BB), dim3(NTHR), 0, stream>>>(x, w, cent, ls, out);
}

// Round 6
// 128.924 us; speedup vs baseline: 1.2489x; 1.2489x over previous
//
#include <hip/hip_runtime.h>
#include <math.h>

#define FIN   64
#define NK    512
#define FOUT  256
#define BB    8             // batch rows per block
#define NTHR  512           // 8 waves
#define RSTR  (NK + 4)      // padded R stride (floats)

__device__ __forceinline__ float dot4(float4 a, float4 b, float s) {
    s = fmaf(a.x, b.x, s);
    s = fmaf(a.y, b.y, s);
    s = fmaf(a.z, b.z, s);
    s = fmaf(a.w, b.w, s);
    return s;
}

// (512,2): 2 blocks/CU worth of waves -> VGPR cap >=128. The (512,4) variant
// capped VGPRs at 64 (8 waves/SIMD cliff) and spilled ~200B/thread to scratch,
// generating ~150MB/dispatch of HBM traffic (R4/R5 counters).
__global__ __launch_bounds__(NTHR, 2) void rbf_fused_kernel(
    const float* __restrict__ x,     // [B][FIN]
    const float* __restrict__ w,     // [FOUT][NK]
    const float* __restrict__ cent,  // [NK][FIN]
    const float* __restrict__ ls,    // [NK]
    float* __restrict__ out)         // [B][FOUT]
{
    __shared__ float xs[BB * FIN];   // 2 KB
    __shared__ float Rs[BB * RSTR];  // 16.5 KB unnormalized rbf
    __shared__ float xsq[BB];
    __shared__ float invs[BB];

    const int tid = threadIdx.x;
    const int b0  = blockIdx.x * BB;

    // ---- stage x tile: 128 float4, coalesced ----
    if (tid < 128) {
        const float4* xg = (const float4*)(x + (size_t)b0 * FIN);
        ((float4*)xs)[tid] = xg[tid];
    }
    __syncthreads();

    // ---- xsq[r]: wave r reduces row r (8 waves <-> 8 rows) ----
    {
        const int wv = tid >> 6, ln = tid & 63;
        const float v = xs[wv * FIN + ln];
        float s = v * v;
        #pragma unroll
        for (int m = 32; m >= 1; m >>= 1) s += __shfl_xor(s, m);
        if (ln == 0) xsq[wv] = s;
    }
    __syncthreads();

    // ---- phase 1: rbf via ||x||^2 - 2 x.c + ||c||^2 ----
    // thread = (kk, jc): jc covers dims [16jc,16jc+16); 4 consecutive lanes
    // form one contiguous 256B cent row read. No runtime-indexed register
    // arrays (scratch trap).
    {
        const int kk = tid >> 2;   // 0..127
        const int jc = tid & 3;
        #pragma unroll 1
        for (int p = 0; p < 4; ++p) {
            const int k = kk + 128 * p;
            const float4* cg = (const float4*)(cent + (size_t)k * FIN + 16 * jc);
            const float4 c0 = cg[0], c1 = cg[1], c2 = cg[2], c3 = cg[3];
            float csq = dot4(c3, c3, dot4(c2, c2, dot4(c1, c1, dot4(c0, c0, 0.f))));
            csq += __shfl_xor(csq, 1);
            csq += __shfl_xor(csq, 2);
            const float e2 = __expf(2.f * ls[k]);
            #pragma unroll
            for (int g = 0; g < 2; ++g) {
                const float* xb = xs + (4 * g) * FIN + 16 * jc;
                float cr0, cr1, cr2, cr3;
                {
                    const float4* xp = (const float4*)(xb + 0 * FIN);
                    cr0 = dot4(xp[3], c3, dot4(xp[2], c2, dot4(xp[1], c1, dot4(xp[0], c0, 0.f))));
                }
                {
                    const float4* xp = (const float4*)(xb + 1 * FIN);
                    cr1 = dot4(xp[3], c3, dot4(xp[2], c2, dot4(xp[1], c1, dot4(xp[0], c0, 0.f))));
                }
                {
                    const float4* xp = (const float4*)(xb + 2 * FIN);
                    cr2 = dot4(xp[3], c3, dot4(xp[2], c2, dot4(xp[1], c1, dot4(xp[0], c0, 0.f))));
                }
                {
                    const float4* xp = (const float4*)(xb + 3 * FIN);
                    cr3 = dot4(xp[3], c3, dot4(xp[2], c2, dot4(xp[1], c1, dot4(xp[0], c0, 0.f))));
                }
                // fold dim-chunks across the 4 jc lanes
                cr0 += __shfl_xor(cr0, 1); cr0 += __shfl_xor(cr0, 2);
                cr1 += __shfl_xor(cr1, 1); cr1 += __shfl_xor(cr1, 2);
                cr2 += __shfl_xor(cr2, 1); cr2 += __shfl_xor(cr2, 2);
                cr3 += __shfl_xor(cr3, 1); cr3 += __shfl_xor(cr3, 2);
                // lane jc owns row 4g+jc — static select, NOT cr[jc]
                const float cr = (jc == 0) ? cr0 : (jc == 1) ? cr1 : (jc == 2) ? cr2 : cr3;
                const int row = 4 * g + jc;
                const float ssq = fmaf(-2.f, cr, xsq[row] + csq);
                Rs[row * RSTR + k] = __expf(-(e2 * ssq));
            }
        }
    }
    __syncthreads();

    // ---- row sums: wave r reduces Rs[r][:] ----
    {
        const int wv = tid >> 6, ln = tid & 63;
        const float4* rp = (const float4*)(Rs + wv * RSTR + 8 * ln);
        const float4 a = rp[0], b = rp[1];
        float s = ((a.x + a.y) + (a.z + a.w)) + ((b.x + b.y) + (b.z + b.w));
        #pragma unroll
        for (int m = 32; m >= 1; m >>= 1) s += __shfl_xor(s, m);
        if (ln == 0) invs[wv] = 1.f / (1e-9f + s);
    }
    __syncthreads();

    // ---- phase 2: out[8][256] = Rs * W^T, W streamed from L2 ----
    // thread: 1 row x 4 cols; wave = 8 rows x 32 cols, disjoint W per wave.
    {
        const int row  = tid & 7;
        const int col0 = 4 * (tid >> 3);
        const float* wp0 = w + (size_t)(col0 + 0) * NK;
        const float* wp1 = w + (size_t)(col0 + 1) * NK;
        const float* wp2 = w + (size_t)(col0 + 2) * NK;
        const float* wp3 = w + (size_t)(col0 + 3) * NK;
        const float* rp  = Rs + row * RSTR;

        float a0 = 0.f, a1 = 0.f, a2 = 0.f, a3 = 0.f;
        float4 rf = *(const float4*)rp;
        float4 w0 = *(const float4*)wp0;
        float4 w1 = *(const float4*)wp1;
        float4 w2 = *(const float4*)wp2;
        float4 w3 = *(const float4*)wp3;

        #pragma unroll 4
        for (int s = 0; s < NK / 4 - 1; ++s) {
            const int kn = 4 * (s + 1);
            const float4 rfn = *(const float4*)(rp + kn);
            const float4 w0n = *(const float4*)(wp0 + kn);
            const float4 w1n = *(const float4*)(wp1 + kn);
            const float4 w2n = *(const float4*)(wp2 + kn);
            const float4 w3n = *(const float4*)(wp3 + kn);
            a0 = dot4(rf, w0, a0);
            a1 = dot4(rf, w1, a1);
            a2 = dot4(rf, w2, a2);
            a3 = dot4(rf, w3, a3);
            rf = rfn; w0 = w0n; w1 = w1n; w2 = w2n; w3 = w3n;
        }
        a0 = dot4(rf, w0, a0);
        a1 = dot4(rf, w1, a1);
        a2 = dot4(rf, w2, a2);
        a3 = dot4(rf, w3, a3);

        const float iv = invs[row];
        float4 o;
        o.x = a0 * iv;
        o.y = a1 * iv;
        o.z = a2 * iv;
        o.w = a3 * iv;
        *(float4*)(out + (size_t)(b0 + row) * FOUT + col0) = o;
    }
}

extern "C" void kernel_launch(void* const* d_in, const int* in_sizes, int n_in,
                              void* d_out, int out_size, void* d_ws, size_t ws_size,
                              hipStream_t stream) {
    const float* x    = (const float*)d_in[0];   // [4096][64]
    const float* w    = (const float*)d_in[1];   // [256][512]
    const float* cent = (const float*)d_in[2];   // [512][64]
    const float* ls   = (const float*)d_in[3];   // [512]
    float* out        = (float*)d_out;           // [4096][256]

    rbf_fused_kernel<<<dim3(4096 / BB), dim3(NTHR), 0, stream>>>(x, w, cent, ls, out);
}

// Round 7
// 83.547 us; speedup vs baseline: 1.9272x; 1.5431x over previous
//
#include <hip/hip_runtime.h>
#include <math.h>

#define FIN   64
#define NK    512
#define FOUT  256
#define BB    16
#define NTHR  512
#define RSTRH 520   // bf16 elems per Rs row: 1040B row stride = 65*16B (aligned, ~min banking)

typedef __attribute__((ext_vector_type(8))) short short8;
typedef __attribute__((ext_vector_type(4))) float f32x4;

#define MFMA(a, b, c) __builtin_amdgcn_mfma_f32_16x16x32_bf16((a), (b), (c), 0, 0, 0)

__device__ __forceinline__ unsigned pack_hi16(float f0, float f1) {
    // result = [f1.hi16 | f0.hi16] : bytes {f0b2,f0b3,f1b2,f1b3}
    return __builtin_amdgcn_perm(__builtin_bit_cast(unsigned, f1),
                                 __builtin_bit_cast(unsigned, f0),
                                 0x07060302u);
}
__device__ __forceinline__ float trunc_bf(float f) {
    return __builtin_bit_cast(float, __builtin_bit_cast(unsigned, f) & 0xFFFF0000u);
}
// pack 8 f32 -> bf16x8 (truncation), leave residual in f (exact Dekker-style split)
__device__ __forceinline__ short8 split_step(float (&f)[8]) {
    union { unsigned u[4]; short8 s; } r;
    #pragma unroll
    for (int i = 0; i < 4; ++i) r.u[i] = pack_hi16(f[2 * i], f[2 * i + 1]);
    #pragma unroll
    for (int i = 0; i < 8; ++i) f[i] = f[i] - trunc_bf(f[i]);
    return r.s;
}
__device__ __forceinline__ short8 pack_bf(const float (&f)[8]) {
    union { unsigned u[4]; short8 s; } r;
    #pragma unroll
    for (int i = 0; i < 4; ++i) r.u[i] = pack_hi16(f[2 * i], f[2 * i + 1]);
    return r.s;
}
__device__ __forceinline__ void load8(const float* p, float (&f)[8]) {
    const float4 a = *(const float4*)p;
    const float4 b = *(const float4*)(p + 4);
    f[0] = a.x; f[1] = a.y; f[2] = a.z; f[3] = a.w;
    f[4] = b.x; f[5] = b.y; f[6] = b.z; f[7] = b.w;
}

__global__ __launch_bounds__(NTHR, 2) void rbf_fused_kernel(
    const float* __restrict__ x,     // [4096][64]
    const float* __restrict__ w,     // [256][512]
    const float* __restrict__ cent,  // [512][64]
    const float* __restrict__ ls,    // [512]
    float* __restrict__ out)         // [4096][256]
{
    __shared__ float csqs[NK];
    __shared__ float e2s[NK];
    __shared__ float xsqs[BB];
    __shared__ float invs[BB];
    __shared__ float rowpart[8][BB];
    __shared__ __align__(16) unsigned short RsHi[BB][RSTRH];
    __shared__ __align__(16) unsigned short RsLo[BB][RSTRH];

    const int tid  = threadIdx.x;
    const int lane = tid & 63;
    const int wv   = tid >> 6;     // 8 waves
    const int arow = lane & 15;    // fragment row / n-col within tile
    const int d0   = (lane >> 4) * 8;
    const int b0   = blockIdx.x * BB;

    // ---- per-lane x fragment: row arow, dims [d0,d0+8) and [32+d0,32+d0+8) ----
    float xf0[8], xf1[8];
    {
        const float* xp = x + (size_t)(b0 + arow) * FIN;
        load8(xp + d0, xf0);
        load8(xp + 32 + d0, xf1);
    }
    // xsq (f32, before splitting)
    {
        float q = 0.f;
        #pragma unroll
        for (int i = 0; i < 8; ++i) q = fmaf(xf0[i], xf0[i], fmaf(xf1[i], xf1[i], q));
        q += __shfl_xor(q, 16);
        q += __shfl_xor(q, 32);
        if (tid < BB) xsqs[tid] = q;   // lanes 0..15 of wave 0 have rows 0..15
    }
    // 3-way split of x fragments (held in regs through phase 2)
    short8 ax1_0 = split_step(xf0), ax2_0 = split_step(xf0), ax3_0 = split_step(xf0);
    short8 ax1_1 = split_step(xf1), ax2_1 = split_step(xf1), ax3_1 = split_step(xf1);

    // ---- csq + exp(2*ls) tables: thread t <-> center t ----
    {
        const float* cp = cent + (size_t)tid * FIN;
        float cs = 0.f;
        #pragma unroll
        for (int j = 0; j < 16; ++j) {
            const float4 c4 = ((const float4*)cp)[j];
            cs = fmaf(c4.x, c4.x, cs); cs = fmaf(c4.y, c4.y, cs);
            cs = fmaf(c4.z, c4.z, cs); cs = fmaf(c4.w, c4.w, cs);
        }
        csqs[tid] = cs;
        e2s[tid]  = __expf(2.f * ls[tid]);
    }
    __syncthreads();

    // ---- phase 2: cross = X * C^T via 3-split MFMA, fused rbf epilogue ----
    float ps[4] = {0.f, 0.f, 0.f, 0.f};
    #pragma unroll 1
    for (int i = 0; i < 4; ++i) {
        const int n0 = 64 * wv + 16 * i;
        float cf0[8], cf1[8];
        {
            const float* cp = cent + (size_t)(n0 + arow) * FIN;
            load8(cp + d0, cf0);
            load8(cp + 32 + d0, cf1);
        }
        const short8 b1_0 = split_step(cf0), b2_0 = split_step(cf0), b3_0 = split_step(cf0);
        const short8 b1_1 = split_step(cf1), b2_1 = split_step(cf1), b3_1 = split_step(cf1);

        f32x4 acc = {0.f, 0.f, 0.f, 0.f};
        acc = MFMA(ax1_0, b1_0, acc);
        acc = MFMA(ax1_0, b2_0, acc);
        acc = MFMA(ax2_0, b1_0, acc);
        acc = MFMA(ax2_0, b2_0, acc);
        acc = MFMA(ax1_0, b3_0, acc);
        acc = MFMA(ax3_0, b1_0, acc);
        acc = MFMA(ax1_1, b1_1, acc);
        acc = MFMA(ax1_1, b2_1, acc);
        acc = MFMA(ax2_1, b1_1, acc);
        acc = MFMA(ax2_1, b2_1, acc);
        acc = MFMA(ax1_1, b3_1, acc);
        acc = MFMA(ax3_1, b1_1, acc);

        // epilogue: C layout col=lane&15, row=(lane>>4)*4+j  [verified m89/m91]
        const int col = n0 + arow;
        const float cq = csqs[col];
        const float e2 = e2s[col];
        #pragma unroll
        for (int j = 0; j < 4; ++j) {
            const int row = (lane >> 4) * 4 + j;
            const float ssq = xsqs[row] + cq - 2.f * acc[j];
            const float rb  = __expf(-(e2 * ssq));
            ps[j] += rb;
            const float lo = rb - trunc_bf(rb);
            RsHi[row][col] = (unsigned short)(__builtin_bit_cast(unsigned, rb) >> 16);
            RsLo[row][col] = (unsigned short)(__builtin_bit_cast(unsigned, lo) >> 16);
        }
    }
    // row sums: fold across the 16 n-lanes, stash per-wave partials
    #pragma unroll
    for (int j = 0; j < 4; ++j) {
        float v = ps[j];
        v += __shfl_xor(v, 1);
        v += __shfl_xor(v, 2);
        v += __shfl_xor(v, 4);
        v += __shfl_xor(v, 8);
        if (arow == 0) rowpart[wv][(lane >> 4) * 4 + j] = v;
    }
    __syncthreads();
    if (tid < BB) {
        float s = 0.f;
        #pragma unroll
        for (int q = 0; q < 8; ++q) s += rowpart[q][tid];
        invs[tid] = 1.f / (1e-9f + s);
    }
    __syncthreads();

    // ---- phase 4: out = R * W^T via 2-split MFMA, W converted on the fly ----
    const int n0 = 32 * wv;   // wave owns cols [n0, n0+32)
    const float* wb0 = w + (size_t)(n0 + arow) * NK;
    const float* wb1 = w + (size_t)(n0 + 16 + arow) * NK;

    f32x4 o0 = {0.f, 0.f, 0.f, 0.f};
    f32x4 o1 = {0.f, 0.f, 0.f, 0.f};
    #pragma unroll 2
    for (int ks = 0; ks < NK / 32; ++ks) {
        const int kb = ks * 32 + d0;
        const short8 ahi = *(const short8*)&RsHi[arow][kb];
        const short8 alo = *(const short8*)&RsLo[arow][kb];
        float wf[8];
        load8(wb0 + kb, wf);
        {
            const short8 whi = split_step(wf);
            const short8 wlo = pack_bf(wf);
            o0 = MFMA(ahi, whi, o0);
            o0 = MFMA(ahi, wlo, o0);
            o0 = MFMA(alo, whi, o0);
        }
        load8(wb1 + kb, wf);
        {
            const short8 whi = split_step(wf);
            const short8 wlo = pack_bf(wf);
            o1 = MFMA(ahi, whi, o1);
            o1 = MFMA(ahi, wlo, o1);
            o1 = MFMA(alo, whi, o1);
        }
    }

    // ---- epilogue: normalize + store ----
    #pragma unroll
    for (int j = 0; j < 4; ++j) {
        const int row = (lane >> 4) * 4 + j;
        const float iv = invs[row];
        out[(size_t)(b0 + row) * FOUT + n0 + arow]      = o0[j] * iv;
        out[(size_t)(b0 + row) * FOUT + n0 + 16 + arow] = o1[j] * iv;
    }
}

extern "C" void kernel_launch(void* const* d_in, const int* in_sizes, int n_in,
                              void* d_out, int out_size, void* d_ws, size_t ws_size,
                              hipStream_t stream) {
    const float* x    = (const float*)d_in[0];   // [4096][64]
    const float* w    = (const float*)d_in[1];   // [256][512]
    const float* cent = (const float*)d_in[2];   // [512][64]
    const float* ls   = (const float*)d_in[3];   // [512]
    float* out        = (float*)d_out;           // [4096][256]

    rbf_fused_kernel<<<dim3(4096 / BB), dim3(NTHR), 0, stream>>>(x, w, cent, ls, out);
}